// Round 15
// baseline (781.188 us; speedup 1.0000x reference)
//
#include <hip/hip_runtime.h>
#include <math.h>

#define NXG 512
#define NPTS (NXG * NXG)
#define NB 4
#define NT 256
#define NM 256
#define K 16                // steps per chunk
#define NCH (NT / K)        // 16 chunks
#define WROWS 128           // window rows (64 interior + 2*32 halo)
#define WCOLS 128           // window cols
#define NTHR 1024           // 32 row-groups x 32 cols; 4x4 cells per thread
#define NTILES 64           // 8x8 tiles (64x64 interior) cover 512x512
#define LROWS 136           // LDS slots: rows -4..131 (direct map slot=row+4)

// ---------------------------------------------------------------------------
__global__ __launch_bounds__(256) void zero_kernel(float4* __restrict__ p) {
    p[blockIdx.x * 256 + threadIdx.x] = make_float4(0.f, 0.f, 0.f, 0.f);
}

// One-time vel2/12 table in field layout.
__global__ __launch_bounds__(256) void vel2_kernel(const float* __restrict__ x,
                                                   float* __restrict__ vel2) {
    int gid = blockIdx.x * 256 + threadIdx.x;
    int b = gid >> 18;
    int idx = gid & (NPTS - 1);
    int i = idx >> 9, j = idx & 511;
    float v;
    if (i < 55 || i >= 457 || j < 55 || j >= 457) v = 1e-6f;
    else if (i >= 128 && i < 384 && j >= 128 && j < 384)
        v = x[(b << 16) | ((i - 128) << 8) | (j - 128)];
    else v = 1.5f;
    float a = (2e-05f * v) / 1e-04f;
    vel2[gid] = a * a * (1.0f / 12.0f);
}

// DPP wave shifts (lane+-1). Cross-thread junk lands only in column-halo
// threads (col 0 / 31) — garbage-tolerant by the 32-wide halo argument.
__device__ __forceinline__ float dpp_left(float v) {
    return __int_as_float(__builtin_amdgcn_mov_dpp(__float_as_int(v),
                                                   0x138, 0xf, 0xf, true));
}
__device__ __forceinline__ float dpp_right(float v) {
    return __int_as_float(__builtin_amdgcn_mov_dpp(__float_as_int(v),
                                                   0x130, 0xf, 0xf, true));
}

// ---------------------------------------------------------------------------
// One row: reads cur rows + old dst[r] (previous field), writes the new
// field IN PLACE into dst[r]. No inj/meas code in the hot path.
// ---------------------------------------------------------------------------
__device__ __forceinline__ void row_calc(
    const float (&cur)[4][4], float (&dst)[4][4],
    const float (&v2R)[4][4], int r,
    const float* __restrict__ xm2, const float* __restrict__ xm1,
    const float* __restrict__ xp1, const float* __restrict__ xp2)
{
    float y[8] = {dpp_left(cur[r][2]), dpp_left(cur[r][3]),
                  cur[r][0], cur[r][1], cur[r][2], cur[r][3],
                  dpp_right(cur[r][0]), dpp_right(cur[r][1])};
#pragma unroll
    for (int c = 0; c < 4; ++c) {
        float cc = cur[r][c];
        float sum1 = (xm1[c] + xp1[c]) + (y[c + 1] + y[c + 3]);
        float sum2 = (xm2[c] + xp2[c]) + (y[c] + y[c + 4]);
        float w = fmaf(-60.0f, cc, fmaf(16.0f, sum1, -sum2));
        dst[r][c] = fmaf(v2R[r][c], w, fmaf(2.0f, cc, -dst[r][c]));
    }
}

// ---------------------------------------------------------------------------
// One step, 4x4 cells: x-halo rows r0-2,r0-1,r0+4,r0+5 from LDS; y-halo DPP.
// New field written in place into nw (old prv); ALL 4 rows published to Ln.
// ---------------------------------------------------------------------------
__device__ __forceinline__ void do_step(
    const float* __restrict__ Lc, float* __restrict__ Ln,
    const float (&v2R)[4][4], float (&cur)[4][4], float (&nw)[4][4],
    int base, int c0)
{
    float4 a4 = *(const float4*)&Lc[(base - 2) * WCOLS + c0];  // row r0-2
    float4 b4 = *(const float4*)&Lc[(base - 1) * WCOLS + c0];  // row r0-1
    float4 c4 = *(const float4*)&Lc[(base + 4) * WCOLS + c0];  // row r0+4
    float4 d4 = *(const float4*)&Lc[(base + 5) * WCOLS + c0];  // row r0+5

    float ha[4] = {a4.x, a4.y, a4.z, a4.w};
    float hb[4] = {b4.x, b4.y, b4.z, b4.w};
    float hc[4] = {c4.x, c4.y, c4.z, c4.w};
    float hd[4] = {d4.x, d4.y, d4.z, d4.w};

    row_calc(cur, nw, v2R, 0, ha, hb, cur[1], cur[2]);
    *(float4*)&Ln[(base + 0) * WCOLS + c0] =
        make_float4(nw[0][0], nw[0][1], nw[0][2], nw[0][3]);
    row_calc(cur, nw, v2R, 1, hb, cur[0], cur[2], cur[3]);
    *(float4*)&Ln[(base + 1) * WCOLS + c0] =
        make_float4(nw[1][0], nw[1][1], nw[1][2], nw[1][3]);
    row_calc(cur, nw, v2R, 2, cur[0], cur[1], cur[3], hc);
    *(float4*)&Ln[(base + 2) * WCOLS + c0] =
        make_float4(nw[2][0], nw[2][1], nw[2][2], nw[2][3]);
    row_calc(cur, nw, v2R, 3, cur[1], cur[2], hc, hd);
    *(float4*)&Ln[(base + 3) * WCOLS + c0] =
        make_float4(nw[3][0], nw[3][1], nw[3][2], nw[3][3]);
}

// ---------------------------------------------------------------------------
// Rare post-step patch: injection add (+ LDS row refresh), then measurement
// reads of the PATCHED new field.
// ---------------------------------------------------------------------------
__device__ __forceinline__ void patch_step(
    float (&f)[4][4], float* __restrict__ Ln, float* __restrict__ out,
    int base, int c0, int injCell, float addv,
    int m1Cell, int m1Addr, int m2Cell, int m2Addr, int n)
{
    if (injCell >= 0) {
#pragma unroll
        for (int r = 0; r < 4; ++r)
#pragma unroll
            for (int c = 0; c < 4; ++c)
                if (((r << 2) | c) == injCell) f[r][c] += addv;
        int ir = injCell >> 2;
#pragma unroll
        for (int r = 0; r < 4; ++r)
            if (r == ir)
                *(float4*)&Ln[(base + r) * WCOLS + c0] =
                    make_float4(f[r][0], f[r][1], f[r][2], f[r][3]);
    }
    if (m1Cell >= 0) {
        float v = 0.0f;
#pragma unroll
        for (int r = 0; r < 4; ++r)
#pragma unroll
            for (int c = 0; c < 4; ++c)
                if (((r << 2) | c) == m1Cell) v = f[r][c];
        out[m1Addr | n] = v;
    }
    if (m2Cell >= 0) {
        float v = 0.0f;
#pragma unroll
        for (int r = 0; r < 4; ++r)
#pragma unroll
            for (int c = 0; c < 4; ++c)
                if (((r << 2) | c) == m2Cell) v = f[r][c];
        out[m2Addr | n] = v;
    }
}

// ---------------------------------------------------------------------------
__global__ __launch_bounds__(NTHR, 4) void chunk_kernel(
    const float* __restrict__ se,      // (64,)
    float* __restrict__ out,           // (4,1,256,256) = [b][m][t]
    const float* __restrict__ gA,      // f_{n0}
    const float* __restrict__ gB,      // f_{n0-1}
    float* __restrict__ wA,            // f_{n0+K}
    float* __restrict__ wB,            // f_{n0+K-1}
    const float* __restrict__ vel2,    // precomputed v2/12, field layout
    const int2* __restrict__ thrTab,   // NTILES x NTHR
    const float* __restrict__ srcT,
    int n0)
{
    __shared__ __align__(16) float L0[LROWS * WCOLS];
    __shared__ __align__(16) float L1[LROWS * WCOLS];

    const int tid = threadIdx.x;
    const int blk = blockIdx.x;
    const int b   = blk >> 6;          // batch
    const int tb  = blk & 63;          // tile
    const int gi0 = (tb >> 3) << 6;
    const int gj0 = (tb & 7) << 6;
    const int bi0 = gi0 - 32;
    const int bj0 = gj0 - 32;

    const int grp = tid >> 5;          // 0..31
    const int r0  = grp << 2;          // own window rows r0..r0+3
    const int c0  = (tid & 31) << 2;   // own window cols
    const int base = r0 + 4;           // LDS slot of own row 0 (slot=row+4)

    // ---- zero halo pad rows (slots 2,3 and 132,133) of both buffers ----
    if (tid < 256) {
        int buf = tid >= 128;
        int q = tid & 127;             // 0..127
        int pr = q >> 5;               // 0..3
        int pc = (q & 31) << 2;
        int slot = (pr < 2) ? (pr + 2) : (pr + 130);   // 2,3,132,133
        float* S = buf ? L1 : L0;
        *(float4*)&S[slot * WCOLS + pc] = make_float4(0.f, 0.f, 0.f, 0.f);
    }

    // ---- prologue: own cells of f_{n0}, f_{n0-1}, vel2 — b128 loads ----
    float curR[4][4], prvR[4][4], v2R[4][4];
    const float* gAb = gA + (b << 18);
    const float* gBb = gB + (b << 18);
    const float* gVb = vel2 + (b << 18);
#pragma unroll
    for (int r = 0; r < 4; ++r) {
        int gi = (bi0 + r0 + r) & 511;
        int gj = (bj0 + c0) & 511;
        float4 cv = *(const float4*)&gAb[(gi << 9) | gj];
        float4 pv = *(const float4*)&gBb[(gi << 9) | gj];
        float4 vv = *(const float4*)&gVb[(gi << 9) | gj];
        curR[r][0] = cv.x; curR[r][1] = cv.y; curR[r][2] = cv.z; curR[r][3] = cv.w;
        prvR[r][0] = pv.x; prvR[r][1] = pv.y; prvR[r][2] = pv.z; prvR[r][3] = pv.w;
        v2R[r][0] = vv.x; v2R[r][1] = vv.y; v2R[r][2] = vv.z; v2R[r][3] = vv.w;
    }

    // ---- inj/meas descriptor ----
    const int2 tw = thrTab[(tb << 10) | tid];
    int injCell = -1;  float injV = 0.0f;
    if (tw.x >= 0) { injCell = tw.x & 15; injV = 0.09f * se[tw.x >> 8]; }
    int m1Cell = -1, m1Addr = 0, m2Cell = -1, m2Addr = 0;
    {
        int h1 = tw.y & 0xFFFF, h2 = (tw.y >> 16) & 0xFFFF;
        if (h1 & 0x8000) { m1Cell = (h1 >> 8) & 15; m1Addr = (b << 16) | ((h1 & 255) << 8); }
        if (h2 & 0x8000) { m2Cell = (h2 >> 8) & 15; m2Addr = (b << 16) | ((h2 & 255) << 8); }
    }
    const bool rare = (injCell >= 0) || (m1Cell >= 0) || (m2Cell >= 0);

    // ---- publish f_{n0} (all own rows) ----
#pragma unroll
    for (int r = 0; r < 4; ++r)
        *(float4*)&L0[(base + r) * WCOLS + c0] =
            make_float4(curR[r][0], curR[r][1], curR[r][2], curR[r][3]);
    __syncthreads();

#pragma unroll 1
    for (int s = 0; s < K; s += 2) {    // 2 steps/iter — body fits I-cache
        float sva = srcT[n0 + s];
        float svb = srcT[n0 + s + 1];

        do_step(L0, L1, v2R, curR, prvR, base, c0);    // prvR <- f_{n+1}
        if (rare) patch_step(prvR, L1, out, base, c0, injCell, injV * sva,
                             m1Cell, m1Addr, m2Cell, m2Addr, n0 + s);
        __syncthreads();

        do_step(L1, L0, v2R, prvR, curR, base, c0);    // curR <- f_{n+2}
        if (rare) patch_step(curR, L0, out, base, c0, injCell, injV * svb,
                             m1Cell, m1Addr, m2Cell, m2Addr, n0 + s + 1);
        if (s + 2 < K) __syncthreads();
    }

    // ---- write back interior: curR = f_{n0+K}, prvR = f_{n0+K-1} ----
    if (r0 >= 32 && r0 < 96 && c0 >= 32 && c0 < 96) {
        int gj = gj0 + (c0 - 32);
#pragma unroll
        for (int r = 0; r < 4; ++r) {
            int gi = gi0 + (r0 - 32) + r;
            *(float4*)&wA[(b << 18) | (gi << 9) | gj] =
                make_float4(curR[r][0], curR[r][1], curR[r][2], curR[r][3]);
            *(float4*)&wB[(b << 18) | (gi << 9) | gj] =
                make_float4(prvR[r][0], prvR[r][1], prvR[r][2], prvR[r][3]);
        }
    }
}

// ---------------------------------------------------------------------------
extern "C" void kernel_launch(void* const* d_in, const int* in_sizes, int n_in,
                              void* d_out, int out_size, void* d_ws, size_t ws_size,
                              hipStream_t stream) {
    const float* x  = (const float*)d_in[0];
    const float* se = (const float*)d_in[1];
    float* out = (float*)d_out;

    float* ws = (float*)d_ws;
    const int FSZ = NB * NPTS;                 // 4 MB per field (floats)
    float* f[4]  = {ws, ws + FSZ, ws + 2 * FSZ, ws + 3 * FSZ};
    float* dVel  = ws + 4 * FSZ;                        // 4 MB
    int2*  dTT   = (int2*)(ws + 5 * FSZ);               // 64*1024 int2
    float* dSrc  = (float*)(ws + 5 * FSZ + NTILES * NTHR * 2);

    static int   h_tt[NTILES * NTHR * 2];
    static float h_src[NT];
    static int   h_mx[NM], h_my[NM];
    for (int m = 0; m < NM; ++m) {
        double theta = (2.0 * M_PI * (double)m) / 256.0;
        h_mx[m] = (int)(256.0 + 200.0 * cos(theta));
        h_my[m] = (int)(256.0 + 200.0 * sin(theta));
    }
    for (int i = 0; i < NTILES * NTHR; ++i) { h_tt[2*i] = -1; h_tt[2*i+1] = 0; }
    for (int tile = 0; tile < NTILES; ++tile) {
        int bi0 = ((tile >> 3) << 6) - 32;
        int bj0 = ((tile & 7) << 6) - 32;
        for (int m = 0; m < NM; ++m) {
            int d = (h_mx[m] - bi0) & 511;
            int e = (h_my[m] - bj0) & 511;
            if (d >= WROWS || e >= WCOLS) continue;
            int tidx = (d >> 2) * 32 + (e >> 2);
            int cell = ((d & 3) << 2) | (e & 3);         // 0..15
            int basei = (tile * NTHR + tidx) * 2;
            if ((m & 3) == 0) h_tt[basei] = ((m >> 2) << 8) | cell;
            if (d >= 32 && d < 96 && e >= 32 && e < 96) {
                int half = 0x8000 | (cell << 8) | m;
                if (!(h_tt[basei + 1] & 0x8000)) h_tt[basei + 1] |= half;
                else                             h_tt[basei + 1] |= half << 16;
            }
        }
    }
    for (int t = 0; t < NT; ++t) {
        float tj  = (float)t * 2e-05f;
        float arg = (float)(2.0 * M_PI * 500.0) * tj;
        float d   = tj - 0.002f;
        float e   = -(d * d) / (float)(2.0 * 0.001 * 0.001);
        h_src[t]  = sinf(arg) * expf(e);
    }
    hipMemcpyAsync(dTT,  h_tt,  sizeof(h_tt),  hipMemcpyHostToDevice, stream);
    hipMemcpyAsync(dSrc, h_src, sizeof(h_src), hipMemcpyHostToDevice, stream);

    // zero chunk-0 input pair (f0A,f0B contiguous = 8 MB = 524288 float4)
    zero_kernel<<<2048, 256, 0, stream>>>((float4*)ws);
    // one-time vel2/12 table
    vel2_kernel<<<NB * NPTS / 256, 256, 0, stream>>>(x, dVel);

    for (int c = 0; c < NCH; ++c) {
        int p = c & 1, q = p ^ 1;
        chunk_kernel<<<NB * NTILES, NTHR, 0, stream>>>(
            se, out,
            f[2 * p], f[2 * p + 1],
            f[2 * q], f[2 * q + 1],
            dVel, dTT, dSrc, c * K);
    }
}